// Round 3
// baseline (463.249 us; speedup 1.0000x reference)
//
#include <hip/hip_runtime.h>
#include <hip/hip_bf16.h>
#include <cstdint>
#include <cstddef>

// ResNet CG-gated basic block, MI355X gfx950.
// conv: block = one 8x8 px tile x 256 outs; 4 waves = 4 out-quarters sharing a
// cooperatively staged A patch (10x10x64ch per cb, double-buffered). B (weights)
// streamed straight to registers per wave, software-pipelined one tap ahead.
// Barriers only at cb boundaries with counted vmcnt(8) (prefetches stay in
// flight). Internals bf16 (MFMA 16x16x32), fp32 accum.

typedef __attribute__((ext_vector_type(8))) short bf16x8;
typedef __attribute__((ext_vector_type(4))) float f32x4;
typedef __attribute__((ext_vector_type(8))) unsigned short u16x8;

#define HP 58
#define WP 58
#define CIN 256
#define NIMG 16

__device__ __forceinline__ unsigned short f2bf(float f) {
  unsigned int u = __float_as_uint(f);
  u += 0x7fffu + ((u >> 16) & 1u);   // RNE
  return (unsigned short)(u >> 16);
}

#define GLOAD16(gp, lp)                                                        \
  __builtin_amdgcn_global_load_lds(                                            \
      (const __attribute__((address_space(1))) void*)(gp),                     \
      (__attribute__((address_space(3))) void*)(lp), 16, 0, 0)

// ---------------------------------------------------------------- hpad borders
__global__ void zero_borders(unsigned short* __restrict__ pad) {
  int b = blockIdx.x;              // 16*58
  int img = b / 58, yp = b - img * 58;
  int tid = threadIdx.x;
  u16x8 z = {0, 0, 0, 0, 0, 0, 0, 0};
  unsigned short* row = pad + ((size_t)(img * HP + yp)) * WP * CIN;
  if (yp == 0 || yp == HP - 1) {
    for (int i = tid; i < WP * CIN / 8; i += 256) ((u16x8*)row)[i] = z;
  } else {
    if (tid < 32) ((u16x8*)row)[tid] = z;                                // x=0
    else if (tid < 64) ((u16x8*)row)[(WP - 1) * CIN / 8 + tid - 32] = z; // x=57
  }
}

// ---------------------------------------------------------------- weights
// w OIHW f32 -> Bt[tap][cb][256 o][64 c] bf16
__global__ void prep_w(const float* __restrict__ wa, const float* __restrict__ wb,
                       unsigned short* __restrict__ bta, unsigned short* __restrict__ btb) {
  int id = blockIdx.x * 256 + threadIdx.x;   // 0 .. 131071
  const float* w = (id < 65536) ? wa : wb;
  unsigned short* bt = (id < 65536) ? bta : btb;
  int oi = id & 65535;
  int o = oi >> 8, i = oi & 255;
  int cb = i >> 6, c = i & 63;
  float v[9];
#pragma unroll
  for (int t = 0; t < 9; ++t) v[t] = w[(size_t)oi * 9 + t];
#pragma unroll
  for (int t = 0; t < 9; ++t)
    bt[((size_t)((t * 4 + cb) * 256 + o)) * 64 + c] = f2bf(v[t]);
}

// ------------------------------------------ x: NCHW f32 -> padded NHWC bf16 (+borders)
__global__ void prep_x(const float* __restrict__ x, unsigned short* __restrict__ xpad) {
  __shared__ float ld[56 * 65];
  int b = blockIdx.x;              // 16*58 padded rows
  int img = b / 58, y = b - img * 58;
  int tid = threadIdx.x;
  unsigned short* row = xpad + ((size_t)(img * HP + y)) * WP * CIN;
  u16x8 z = {0, 0, 0, 0, 0, 0, 0, 0};
  if (y == 0 || y == HP - 1) {
#pragma unroll
    for (int it = 0; it < 8; ++it) {
      int i = it * 256 + tid;
      if (i < WP * CIN / 8) ((u16x8*)row)[i] = z;
    }
    return;
  }
  if (tid < 32) ((u16x8*)row)[tid] = z;
  else if (tid < 64) ((u16x8*)row)[(WP - 1) * CIN / 8 + tid - 32] = z;
  int ys = y - 1;
  for (int cb = 0; cb < 4; ++cb) {
    __syncthreads();
#pragma unroll
    for (int it = 0; it < 14; ++it) {
      int i = tid + it * 256;                      // 64 ch * 56 x
      int cl = i / 56, xx = i - cl * 56;
      ld[xx * 65 + cl] = x[((size_t)(img * 256 + cb * 64 + cl) * 56 + ys) * 56 + xx];
    }
    __syncthreads();
#pragma unroll
    for (int it = 0; it < 14; ++it) {
      int j = tid + it * 256;
      int xx = j >> 6, c = j & 63;
      row[(xx + 1) * CIN + cb * 64 + c] = f2bf(ld[xx * 65 + c]);
    }
  }
}

// ---------------------------------------------------------------- CG conv + BN
// grid = 784 blocks (one per 8x8 tile), 256 threads. wave wid = out-quarter.
template <int LAYER>
__global__ __launch_bounds__(256, 2)
void conv_cg(const unsigned short* __restrict__ inp,   // [16][58][58][256] bf16
             const unsigned short* __restrict__ Bt,    // [9][4][256][64] bf16
             const float* __restrict__ theta,
             const float* __restrict__ gammav,
             const float* __restrict__ betav,
             const float* __restrict__ meanv,
             const float* __restrict__ varv,
             unsigned short* __restrict__ hout,        // LAYER==1
             const float* __restrict__ xres,           // LAYER==2
             float* __restrict__ dout)                 // LAYER==2
{
  __shared__ alignas(16) char smem[34816];   // A dbuf 2x12800 | epilogue 4x8704
  unsigned short* sA0 = (unsigned short*)smem;
  unsigned short* sA1 = (unsigned short*)(smem + 12800);

  const int tid = threadIdx.x;
  const int lane = tid & 63;
  const int wid = tid >> 6;                   // out-quarter
  const int l15 = lane & 15, l4 = lane >> 4;

  int bx = blockIdx.x;
  bx = (bx & 7) * 98 + (bx >> 3);             // XCD-bijective swizzle (784=8*98)
  const int img = bx / 49;
  const int rr = bx - img * 49;
  const int ty = rr / 7, tx = rr - ty * 7;
  const int y0 = ty * 8 + 1, x0 = tx * 8 + 1;
  const size_t img_base = (size_t)img * (HP * WP * CIN);
  const unsigned short* acorner =
      inp + img_base + ((size_t)((y0 - 1) * WP + (x0 - 1))) * CIN;

  // A-staging per-lane constants (unit u = it*256+tid; 800 16B-units per chunk)
  int srcoff[4];
#pragma unroll
  for (int it = 0; it < 4; ++it) {
    int u = it * 256 + tid;
    int ppx = u >> 3, s = u & 7;
    int py = ppx / 10, pxx = ppx - py * 10;
    srcoff[it] = (py * WP + pxx) * CIN + ((s ^ (ppx & 7)) << 3);
  }
  const int blane = l15 * 64 + l4 * 8;
  const unsigned short* Bw = Bt + (size_t)wid * 64 * 64;   // wave's out rows

  f32x4 acc[4][4], ypv[4][4];
  const f32x4 fzero = {0.f, 0.f, 0.f, 0.f};
#pragma unroll
  for (int i = 0; i < 4; ++i)
#pragma unroll
    for (int j = 0; j < 4; ++j) { acc[i][j] = fzero; ypv[i][j] = fzero; }

  auto stageA = [&](unsigned short* buf, int cb) {
#pragma unroll
    for (int it = 0; it < 4; ++it) {
      if (it * 256 + tid < 800)
        GLOAD16(acorner + cb * 64 + srcoff[it], buf + (it * 256 + wid * 64) * 8);
    }
  };
  auto loadB = [&](bf16x8 (&dst)[4][2], int tapcb) {
    const unsigned short* bb = Bw + (size_t)tapcb * 16384 + blane;
#pragma unroll
    for (int ni = 0; ni < 4; ++ni)
#pragma unroll
      for (int ks = 0; ks < 2; ++ks)
        dst[ni][ks] = *(const bf16x8*)(bb + ni * 1024 + ks * 32);
  };
  auto doTap = [&](const unsigned short* sAb, bf16x8 (&B)[4][2], int dy, int dxx) {
#pragma unroll
    for (int ks = 0; ks < 2; ++ks) {
      bf16x8 av[4];
#pragma unroll
      for (int mi = 0; mi < 4; ++mi) {
        int ppx = (mi * 2 + (l15 >> 3) + dy + 1) * 10 + (l15 & 7) + dxx + 1;
        av[mi] = *(const bf16x8*)(sAb + ppx * 64 +
                                  (((ks * 4 + l4) ^ (ppx & 7)) << 3));
      }
#pragma unroll
      for (int mi = 0; mi < 4; ++mi)
#pragma unroll
        for (int ni = 0; ni < 4; ++ni)
          acc[mi][ni] = __builtin_amdgcn_mfma_f32_16x16x32_bf16(
              av[mi], B[ni][ks], acc[mi][ni], 0, 0, 0);
    }
  };

  bf16x8 bb0[4][2], bb1[4][2];
  stageA(sA0, 0);
  loadB(bb0, 0);
  asm volatile("s_waitcnt vmcnt(8)" ::: "memory");
  __builtin_amdgcn_s_barrier();
  __builtin_amdgcn_sched_barrier(0);

#pragma unroll
  for (int cb = 0; cb < 4; ++cb) {
    unsigned short* sCur = (cb & 1) ? sA1 : sA0;
    unsigned short* sNxt = (cb & 1) ? sA0 : sA1;
    if (cb < 3) stageA(sNxt, cb + 1);         // into the buffer freed at last barrier
#pragma unroll
    for (int tap = 0; tap < 9; ++tap) {
      const int dy = tap / 3 - 1, dxx = tap % 3 - 1;
      const int ntap = (tap < 8) ? tap + 1 : 0;
      const int ncb = (tap < 8) ? cb : cb + 1;
      if (!(cb == 3 && tap == 8)) {           // prefetch next tap's B into other set
        if (((cb + tap) & 1) == 0) loadB(bb1, ntap * 4 + ncb);
        else                       loadB(bb0, ntap * 4 + ncb);
      }
      if (((cb + tap) & 1) == 0) doTap(sCur, bb0, dy, dxx);
      else                       doTap(sCur, bb1, dy, dxx);
    }
    if (cb < 3) {
      // in-order vmcnt retire: allowing 8 newest (B prefetch) forces A done
      asm volatile("s_waitcnt vmcnt(8)" ::: "memory");
      __builtin_amdgcn_s_barrier();
      __builtin_amdgcn_sched_barrier(0);
    }
    if (cb == 0) {
#pragma unroll
      for (int i = 0; i < 4; ++i)
#pragma unroll
        for (int j = 0; j < 4; ++j) { ypv[i][j] = acc[i][j]; acc[i][j] = fzero; }
    }
  }
  __syncthreads();   // full drain; sA LDS reused as epilogue scratch

  // ---- epilogue: gate + BN (+relu / +residual); per-wave private sep region
  float* sep = (float*)smem + wid * 2176;     // [32 px][68] f32
  float th[4], sc[4], bi[4];
#pragma unroll
  for (int ni = 0; ni < 4; ++ni) {
    int o = wid * 64 + ni * 16 + l15;
    th[ni] = theta[o];
    float inv = gammav[o] * rsqrtf(varv[o] + 1e-5f);
    sc[ni] = inv;
    bi[ni] = betav[o] - meanv[o] * inv;
  }
#pragma unroll
  for (int r = 0; r < 2; ++r) {
#pragma unroll
    for (int mh = 0; mh < 2; ++mh) {
      int mi = r * 2 + mh;
#pragma unroll
      for (int ni = 0; ni < 4; ++ni)
#pragma unroll
        for (int q = 0; q < 4; ++q) {
          int rowl = mh * 16 + l4 * 4 + q;     // 0..31
          float yp = ypv[mi][ni][q], yr = acc[mi][ni][q];
          float dg = 1.f / (1.f + __expf(-2.f * (yp - th[ni])));
          float v = (yp + dg * yr) * sc[ni] + bi[ni];
          if (LAYER == 1) v = fmaxf(v, 0.f);
          sep[rowl * 68 + ni * 16 + l15] = v;
        }
    }
    if (LAYER == 1) {
#pragma unroll
      for (int it = 0; it < 4; ++it) {
        int u = it * 64 + lane;                // 32px * 8 octet-units
        int pxl = u >> 3, s = u & 7;
        int m = r * 32 + pxl;
        int ry = m >> 3, rx = m & 7;
        u16x8 tv;
#pragma unroll
        for (int e = 0; e < 8; ++e) tv[e] = f2bf(sep[pxl * 68 + s * 8 + e]);
        *(u16x8*)(hout + img_base +
                  ((size_t)((y0 + ry) * WP + (x0 + rx))) * CIN + wid * 64 + s * 8) = tv;
      }
    } else {
#pragma unroll
      for (int it = 0; it < 8; ++it) {
        int idx = it * 64 + lane;              // 64oc * 4rows * 2halves
        int oc = idx >> 3, t = idx & 7;
        int row4 = t >> 1, half = t & 1;
        int pxl = row4 * 8 + half * 4;
        int gy = y0 - 1 + r * 4 + row4, gx = x0 - 1 + half * 4;
        size_t gb = ((size_t)(img * 256 + wid * 64 + oc) * 56 + gy) * 56 + gx;
        const float4 xa = *(const float4*)(xres + gb);
        float4 o4;
        o4.x = fmaxf(xa.x + sep[(pxl + 0) * 68 + oc], 0.f);
        o4.y = fmaxf(xa.y + sep[(pxl + 1) * 68 + oc], 0.f);
        o4.z = fmaxf(xa.z + sep[(pxl + 2) * 68 + oc], 0.f);
        o4.w = fmaxf(xa.w + sep[(pxl + 3) * 68 + oc], 0.f);
        *(float4*)(dout + gb) = o4;
      }
    }
  }
}

// ----------------------------------------------------------------
extern "C" void kernel_launch(void* const* d_in, const int* in_sizes, int n_in,
                              void* d_out, int out_size, void* d_ws, size_t ws_size,
                              hipStream_t stream) {
  const float* x    = (const float*)d_in[0];
  const float* w_a  = (const float*)d_in[1];
  const float* th_a = (const float*)d_in[2];
  const float* ga_a = (const float*)d_in[3];
  const float* be_a = (const float*)d_in[4];
  const float* mu_a = (const float*)d_in[5];
  const float* va_a = (const float*)d_in[6];
  const float* w_b  = (const float*)d_in[7];
  const float* th_b = (const float*)d_in[8];
  const float* ga_b = (const float*)d_in[9];
  const float* be_b = (const float*)d_in[10];
  const float* mu_b = (const float*)d_in[11];
  const float* va_b = (const float*)d_in[12];
  float* out = (float*)d_out;

  char* ws = (char*)d_ws;
  unsigned short* xpad = (unsigned short*)ws;
  unsigned short* hpad = (unsigned short*)(ws + 27558912);
  unsigned short* bta  = (unsigned short*)(ws + 2 * 27558912);
  unsigned short* btb  = (unsigned short*)(ws + 2 * 27558912 + 1179648);
  (void)ws_size; (void)in_sizes; (void)n_in; (void)out_size;

  hipLaunchKernelGGL(zero_borders, dim3(NIMG * HP), dim3(256), 0, stream, hpad);
  hipLaunchKernelGGL(prep_w, dim3(512), dim3(256), 0, stream, w_a, w_b, bta, btb);
  hipLaunchKernelGGL(prep_x, dim3(NIMG * HP), dim3(256), 0, stream, x, xpad);

  hipLaunchKernelGGL((conv_cg<1>), dim3(784), dim3(256), 0, stream,
                     xpad, bta, th_a, ga_a, be_a, mu_a, va_a,
                     hpad, (const float*)nullptr, (float*)nullptr);
  hipLaunchKernelGGL((conv_cg<2>), dim3(784), dim3(256), 0, stream,
                     hpad, btb, th_b, ga_b, be_b, mu_b, va_b,
                     (unsigned short*)nullptr, x, out);
}